// Round 1
// baseline (252.953 us; speedup 1.0000x reference)
//
#include <hip/hip_runtime.h>
#include <stdint.h>

#define NT   256
#define KTOP 100
#define CAP  256
#define Wdim 128
#define Hdim 128
#define HW   (128 * 128)
#define Cdim 80
#define Bdim 16

__device__ __forceinline__ bool precedes(float av, uint32_t ai, float bv, uint32_t bi) {
    // "a before b" in top_k order: larger value first; tie -> smaller index first
    return (av > bv) || (av == bv && ai < bi);
}

// Selects top-KTOP of vals[0..NITEMS) (all vals >= 0), writing sorted (value desc,
// index asc) results to cand_v/cand_i[0..KTOP). Uses 256 threads.
// hist: 256 u32, wsum: 4 u32, scal: 8 u32 LDS scratch.
template<int NITEMS>
__device__ void topk_select(float* vals, float* cand_v, uint32_t* cand_i,
                            uint32_t* hist, uint32_t* wsum, uint32_t* scal)
{
    const int tid  = threadIdx.x;
    const int lane = tid & 63;
    const int wid  = tid >> 6;
    constexpr int NPT = (NITEMS + NT - 1) / NT;

    // ---- count strictly-positive entries ----
    if (tid == 0) scal[4] = 0;
    __syncthreads();
    {
        uint32_t c = 0;
        for (int j = 0; j < NPT; ++j) {
            int p = tid + NT * j;
            if (NITEMS % NT != 0) { if (p >= NITEMS) break; }
            if (vals[p] > 0.0f) c++;
        }
        atomicAdd(&scal[4], c);
    }
    __syncthreads();
    const uint32_t n_pos = scal[4];
    const bool fast_ok = (n_pos >= KTOP);

    uint32_t prefix = 0, mask = 0;
    uint32_t cnt_gt = 0, rank_rem = KTOP, cand_total = 0;

    if (fast_ok) {
        const int shifts[3] = {23, 15, 7};
        for (int lev = 0; lev < 3; ++lev) {
            const int shift = shifts[lev];
            hist[tid] = 0;
            __syncthreads();
            for (int j = 0; j < NPT; ++j) {
                int p = tid + NT * j;
                if (NITEMS % NT != 0) { if (p >= NITEMS) break; }
                float v = vals[p];
                if (v > 0.0f) {
                    uint32_t key = __float_as_uint(v);
                    if ((key & mask) == prefix)
                        atomicAdd(&hist[(key >> shift) & 0xFFu], 1u);
                }
            }
            __syncthreads();
            // suffix sums over bins (bin 255 .. 0), via per-wave inclusive scan
            int bin = 255 - tid;
            uint32_t h = hist[bin];
            uint32_t s = h;
            for (int d = 1; d < 64; d <<= 1) {
                uint32_t n = __shfl_up(s, d);
                if (lane >= d) s += n;
            }
            if (lane == 63) wsum[wid] = s;
            __syncthreads();
            uint32_t off = 0;
            for (int w2 = 0; w2 < wid; ++w2) off += wsum[w2];
            s += off;                      // S_incl(bin) = count of keys in bins >= bin
            uint32_t s_excl = s - h;       // count of keys in bins > bin
            if (s_excl < rank_rem && rank_rem <= s) {
                scal[0] = (uint32_t)bin; scal[1] = s_excl; scal[2] = h;
            }
            __syncthreads();
            uint32_t b  = scal[0];
            uint32_t sg = scal[1];
            uint32_t hb = scal[2];
            prefix |= b << shift;
            mask   |= 0xFFu << shift;
            cnt_gt += sg;
            rank_rem -= sg;
            cand_total = cnt_gt + hb;
            if (cand_total <= CAP) break;
        }
    }

    if (fast_ok && cand_total <= CAP) {
        // ---- compact candidates: key-masked-prefix >= selected prefix ----
        if (tid == 0) scal[3] = 0;
        __syncthreads();
        for (int j = 0; j < NPT; ++j) {
            int p = tid + NT * j;
            if (NITEMS % NT != 0) { if (p >= NITEMS) break; }
            float v = vals[p];
            if (v > 0.0f) {
                uint32_t key = __float_as_uint(v);
                if ((key & mask) >= prefix) {
                    uint32_t slot = atomicAdd(&scal[3], 1u);
                    cand_v[slot] = v;
                    cand_i[slot] = (uint32_t)p;
                }
            }
        }
        __syncthreads();
        if (tid >= (int)cand_total) { cand_v[tid] = -1.0f; cand_i[tid] = 0x7FFFFFFFu; }
        __syncthreads();
        // ---- bitonic sort CAP entries, best-first ----
        for (uint32_t k = 2; k <= CAP; k <<= 1) {
            for (uint32_t j2 = k >> 1; j2 > 0; j2 >>= 1) {
                uint32_t ixj = (uint32_t)tid ^ j2;
                if (ixj > (uint32_t)tid) {
                    float    av = cand_v[tid], bv = cand_v[ixj];
                    uint32_t ai = cand_i[tid], bi = cand_i[ixj];
                    bool up = (((uint32_t)tid & k) == 0);
                    bool ap = precedes(av, ai, bv, bi);
                    if (up ? !ap : ap) {
                        cand_v[tid] = bv; cand_v[ixj] = av;
                        cand_i[tid] = bi; cand_i[ixj] = ai;
                    }
                }
                __syncthreads();
            }
        }
    } else {
        // ---- fully-general fallback: iterative extraction (handles zeros/ties) ----
        float bv; uint32_t bi;
        auto rescan = [&]() {
            bv = -1.0f; bi = 0xFFFFFFFFu;
            for (int j = 0; j < NPT; ++j) {
                int p = tid + NT * j;
                if (NITEMS % NT != 0) { if (p >= NITEMS) break; }
                float v = vals[p];
                if (v > bv) { bv = v; bi = (uint32_t)p; }
            }
        };
        rescan();
        for (int it = 0; it < KTOP; ++it) {
            float rv = bv; uint32_t ri = bi;
            for (int d = 32; d > 0; d >>= 1) {
                float    ov = __shfl_xor(rv, d);
                uint32_t oi = __shfl_xor(ri, d);
                if (precedes(ov, oi, rv, ri)) { rv = ov; ri = oi; }
            }
            if (lane == 0) { hist[wid] = __float_as_uint(rv); hist[4 + wid] = ri; }
            __syncthreads();
            if (tid == 0) {
                float gv = __uint_as_float(hist[0]); uint32_t gi = hist[4];
                for (int w2 = 1; w2 < 4; ++w2) {
                    float    ov = __uint_as_float(hist[w2]);
                    uint32_t oi = hist[4 + w2];
                    if (precedes(ov, oi, gv, gi)) { gv = ov; gi = oi; }
                }
                cand_v[it] = gv; cand_i[it] = gi;
                scal[6] = gi;
            }
            __syncthreads();
            uint32_t gi = scal[6];
            if ((int)(gi & (NT - 1)) == tid) {
                vals[gi] = -1.0f;
                rescan();
            }
            __syncthreads();
        }
    }
}

// Kernel 1: per-(b,c) 3x3 NMS + per-class top-100
__global__ void nms_topk_kernel(const float* __restrict__ heat,
                                float* __restrict__ scores_ws,
                                int* __restrict__ inds_ws)
{
    __shared__ float    vals[HW];      // 64 KB
    __shared__ uint32_t hist[256];
    __shared__ float    cand_v[CAP];
    __shared__ uint32_t cand_i[CAP];
    __shared__ uint32_t wsum[4];
    __shared__ uint32_t scal[8];

    const int tid = threadIdx.x;
    const int bc  = blockIdx.x;                     // b*C + c
    const float* plane = heat + (size_t)bc * HW;

    float cen[64];
    // vertical 3-max -> LDS, keep center in registers
    #pragma unroll
    for (int j = 0; j < 64; ++j) {
        int p = tid + NT * j;
        int y = p >> 7;
        float v = plane[p];
        cen[j] = v;
        float m = v;
        if (y > 0)        m = fmaxf(m, plane[p - Wdim]);
        if (y < Hdim - 1) m = fmaxf(m, plane[p + Wdim]);
        vals[p] = m;
    }
    __syncthreads();
    // horizontal 3-max of vertical maxes; NMS keep-if-equal
    #pragma unroll
    for (int j = 0; j < 64; ++j) {
        int p = tid + NT * j;
        int x = p & (Wdim - 1);
        float m = vals[p];
        if (x > 0)        m = fmaxf(m, vals[p - 1]);
        if (x < Wdim - 1) m = fmaxf(m, vals[p + 1]);
        cen[j] = (m == cen[j]) ? cen[j] : 0.0f;
    }
    __syncthreads();
    #pragma unroll
    for (int j = 0; j < 64; ++j) {
        int p = tid + NT * j;
        vals[p] = cen[j];
    }
    __syncthreads();

    topk_select<HW>(vals, cand_v, cand_i, hist, wsum, scal);

    if (tid < KTOP) {
        scores_ws[(size_t)bc * KTOP + tid] = cand_v[tid];
        inds_ws[(size_t)bc * KTOP + tid]   = (int)cand_i[tid];
    }
}

// Kernel 2: per-batch global top-100 over C*K scores + gather + bbox epilogue
__global__ void global_topk_kernel(const float* __restrict__ scores_ws,
                                   const int* __restrict__ inds_ws,
                                   const float* __restrict__ wh,
                                   const float* __restrict__ reg,
                                   float* __restrict__ out)
{
    constexpr int N2 = Cdim * KTOP;    // 8000
    __shared__ float    vals[N2];      // 31.25 KB
    __shared__ uint32_t hist[256];
    __shared__ float    cand_v[CAP];
    __shared__ uint32_t cand_i[CAP];
    __shared__ uint32_t wsum[4];
    __shared__ uint32_t scal[8];

    const int tid = threadIdx.x;
    const int b   = blockIdx.x;

    for (int i = tid; i < N2; i += NT)
        vals[i] = scores_ws[(size_t)b * N2 + i];
    __syncthreads();

    topk_select<N2>(vals, cand_v, cand_i, hist, wsum, scal);

    if (tid < KTOP) {
        float    sc   = cand_v[tid];
        uint32_t ind2 = cand_i[tid];
        uint32_t cls  = ind2 / KTOP;
        int spatial   = inds_ws[(size_t)b * N2 + ind2];
        float ysf = (float)(spatial >> 7);
        float xsf = (float)(spatial & (Wdim - 1));
        float rx = reg[((size_t)b * 2 + 0) * HW + spatial];
        float ry = reg[((size_t)b * 2 + 1) * HW + spatial];
        float ww = wh [((size_t)b * 2 + 0) * HW + spatial];
        float hh = wh [((size_t)b * 2 + 1) * HW + spatial];
        float xb = xsf + rx, yb = ysf + ry;
        float* o = out + ((size_t)b * KTOP + tid) * 6;
        o[0] = xb - ww * 0.5f;
        o[1] = yb - hh * 0.5f;
        o[2] = xb + ww * 0.5f;
        o[3] = yb + hh * 0.5f;
        o[4] = sc;
        o[5] = (float)cls;
    }
}

extern "C" void kernel_launch(void* const* d_in, const int* in_sizes, int n_in,
                              void* d_out, int out_size, void* d_ws, size_t ws_size,
                              hipStream_t stream)
{
    const float* heat = (const float*)d_in[0];
    const float* wh   = (const float*)d_in[1];
    const float* reg  = (const float*)d_in[2];
    float* out = (float*)d_out;

    float* scores_ws = (float*)d_ws;
    int*   inds_ws   = (int*)((char*)d_ws + (size_t)Bdim * Cdim * KTOP * sizeof(float));

    nms_topk_kernel<<<Bdim * Cdim, NT, 0, stream>>>(heat, scores_ws, inds_ws);
    global_topk_kernel<<<Bdim, NT, 0, stream>>>(scores_ws, inds_ws, wh, reg, out);
}

// Round 2
// 245.299 us; speedup vs baseline: 1.0312x; 1.0312x over previous
//
#include <hip/hip_runtime.h>
#include <stdint.h>

#define NT1  256
#define NT2  1024
#define KTOP 100
#define CAPC 256     // candidate cap after radix narrowing
#define CAPP 4096    // compacted local-maxima pair capacity (mean ~1850 for iid uniform)
#define Wdim 128
#define Hdim 128
#define HW   (128 * 128)
#define Cdim 80
#define Bdim 16

__device__ __forceinline__ bool precedes(float av, uint32_t ai, float bv, uint32_t bi) {
    // "a before b" in top_k order: larger value first; tie -> smaller index first
    return (av > bv) || (av == bv && ai < bi);
}

// ---------------------------------------------------------------------------
// Kernel 1: per-(b,c) 3x3 NMS (register/shfl, no LDS plane) + compact maxima
//           + radix-select top-100 over compacted pairs + rank-order output
// ---------------------------------------------------------------------------
__global__ __launch_bounds__(NT1, 4)
void nms_topk_kernel(const float* __restrict__ heat,
                     float* __restrict__ scores_ws,
                     int* __restrict__ inds_ws)
{
    __shared__ float    pv[CAPP];
    __shared__ uint32_t pi[CAPP];
    __shared__ uint32_t hist[256];
    __shared__ float    cv[CAPC];
    __shared__ uint32_t ci[CAPC];
    __shared__ uint32_t wsum[4];
    __shared__ uint32_t scal[8];

    const int tid  = threadIdx.x;
    const int lane = tid & 63;
    const int wid  = tid >> 6;
    const int bc   = blockIdx.x;
    const float*  plane  = heat + (size_t)bc * HW;
    const float4* plane4 = (const float4*)plane;

    if (tid == 0) scal[5] = 0;
    __syncthreads();

    // ---- NMS + compact local maxima (pairs) ----
    #pragma unroll 4
    for (int j = 0; j < 16; ++j) {
        int f = tid + NT1 * j;           // float4 index 0..4095; row = 32 float4s
        int y = f >> 5;
        float4 c4 = plane4[f];
        float4 u4 = (y > 0)        ? plane4[f - 32] : c4;
        float4 d4 = (y < Hdim - 1) ? plane4[f + 32] : c4;
        float vm0 = fmaxf(c4.x, fmaxf(u4.x, d4.x));
        float vm1 = fmaxf(c4.y, fmaxf(u4.y, d4.y));
        float vm2 = fmaxf(c4.z, fmaxf(u4.z, d4.z));
        float vm3 = fmaxf(c4.w, fmaxf(u4.w, d4.w));
        float vl = __shfl_up(vm3, 1);    // prev float4's comp3 (same wave: f is lane-contig)
        float vr = __shfl_down(vm0, 1);  // next float4's comp0
        bool has_l = (f & 31) != 0;      // x0 > 0
        bool has_r = (f & 31) != 31;     // x3 < 127
        float h0 = fmaxf(vm0, vm1); if (has_l) h0 = fmaxf(h0, vl);
        float h1 = fmaxf(vm0, fmaxf(vm1, vm2));
        float h2 = fmaxf(vm1, fmaxf(vm2, vm3));
        float h3 = fmaxf(vm2, vm3); if (has_r) h3 = fmaxf(h3, vr);
        bool k0 = (h0 == c4.x) && (c4.x > 0.0f);
        bool k1 = (h1 == c4.y) && (c4.y > 0.0f);
        bool k2 = (h2 == c4.z) && (c4.z > 0.0f);
        bool k3 = (h3 == c4.w) && (c4.w > 0.0f);
        int nk = (int)k0 + (int)k1 + (int)k2 + (int)k3;
        if (nk) {
            uint32_t pos = atomicAdd(&scal[5], (uint32_t)nk);
            int p = f << 2;
            if (k0 && pos < CAPP) { pv[pos] = c4.x; pi[pos] = p + 0; pos++; }
            if (k1 && pos < CAPP) { pv[pos] = c4.y; pi[pos] = p + 1; pos++; }
            if (k2 && pos < CAPP) { pv[pos] = c4.z; pi[pos] = p + 2; pos++; }
            if (k3 && pos < CAPP) { pv[pos] = c4.w; pi[pos] = p + 3; pos++; }
        }
    }
    __syncthreads();
    const uint32_t n = scal[5];

    bool fast = (n >= KTOP) && (n <= CAPP);
    uint32_t prefix = 0, mask = 0, rank_rem = KTOP, cnt_gt = 0, cand_total = 0;

    if (fast) {
        const int shifts[3] = {23, 15, 7};
        for (int lev = 0; lev < 3; ++lev) {
            const int shift = shifts[lev];
            hist[tid] = 0;
            __syncthreads();
            for (uint32_t i = tid; i < n; i += NT1) {
                uint32_t key = __float_as_uint(pv[i]);
                if ((key & mask) == prefix)
                    atomicAdd(&hist[(key >> shift) & 0xFFu], 1u);
            }
            __syncthreads();
            int bin = 255 - tid;
            uint32_t h = hist[bin];
            uint32_t s = h;
            for (int d = 1; d < 64; d <<= 1) {
                uint32_t nn = __shfl_up(s, d);
                if (lane >= d) s += nn;
            }
            if (lane == 63) wsum[wid] = s;
            __syncthreads();
            uint32_t off = 0;
            for (int w2 = 0; w2 < wid; ++w2) off += wsum[w2];
            s += off;                  // count of keys in bins >= bin (within prefix)
            uint32_t s_ex = s - h;     // count in bins > bin
            if (s_ex < rank_rem && rank_rem <= s) {
                scal[0] = (uint32_t)bin; scal[1] = s_ex; scal[2] = h;
            }
            __syncthreads();
            prefix  |= scal[0] << shift;
            mask    |= 0xFFu << shift;
            cnt_gt  += scal[1];
            rank_rem -= scal[1];
            cand_total = cnt_gt + scal[2];
            if (cand_total <= CAPC) break;
        }
    }

    if (fast && cand_total <= CAPC) {
        // ---- compact candidates ----
        if (tid == 0) scal[3] = 0;
        __syncthreads();
        for (uint32_t i = tid; i < n; i += NT1) {
            uint32_t key = __float_as_uint(pv[i]);
            if ((key & mask) >= prefix) {
                uint32_t slot = atomicAdd(&scal[3], 1u);
                cv[slot] = pv[i]; ci[slot] = pi[i];
            }
        }
        __syncthreads();
        const uint32_t ct = scal[3];
        // ---- barrier-free rank sort (ct <= 256), broadcast LDS reads ----
        if (tid < (int)ct) {
            float av = cv[tid]; uint32_t ai = ci[tid];
            uint32_t rank = 0;
            for (uint32_t j2 = 0; j2 < ct; ++j2)
                rank += precedes(cv[j2], ci[j2], av, ai) ? 1u : 0u;
            if (rank < KTOP) {
                scores_ws[(size_t)bc * KTOP + rank] = av;
                inds_ws[(size_t)bc * KTOP + rank]   = (int)ai;
            }
        }
    } else {
        // ---- fully-general fallback: iterative extraction w/ NMS recompute ----
        float lastv = __uint_as_float(0x7F800000u);   // +inf sentinel
        uint32_t lasti = 0xFFFFFFFFu;
        for (int it = 0; it < KTOP; ++it) {
            float bv = -1.0f; uint32_t bi = 0xFFFFFFFFu;
            for (int i2 = 0; i2 < HW / NT1; ++i2) {
                int p = tid + NT1 * i2;
                int y = p >> 7, x = p & (Wdim - 1);
                float v = plane[p];
                float hm = v;
                for (int dy = -1; dy <= 1; ++dy)
                    for (int dx = -1; dx <= 1; ++dx) {
                        int yy = y + dy, xx = x + dx;
                        if (yy >= 0 && yy < Hdim && xx >= 0 && xx < Wdim)
                            hm = fmaxf(hm, plane[yy * Wdim + xx]);
                    }
                float nv = (hm == v) ? v : 0.0f;
                if (precedes(lastv, lasti, nv, (uint32_t)p) &&
                    precedes(nv, (uint32_t)p, bv, bi)) { bv = nv; bi = (uint32_t)p; }
            }
            for (int d = 32; d > 0; d >>= 1) {
                float    ov = __shfl_xor(bv, d);
                uint32_t oi = __shfl_xor(bi, d);
                if (precedes(ov, oi, bv, bi)) { bv = ov; bi = oi; }
            }
            if (lane == 0) { hist[wid] = __float_as_uint(bv); hist[4 + wid] = bi; }
            __syncthreads();
            if (tid == 0) {
                float gv = __uint_as_float(hist[0]); uint32_t gi = hist[4];
                for (int w2 = 1; w2 < 4; ++w2) {
                    float    ov = __uint_as_float(hist[w2]);
                    uint32_t oi = hist[4 + w2];
                    if (precedes(ov, oi, gv, gi)) { gv = ov; gi = oi; }
                }
                scores_ws[(size_t)bc * KTOP + it] = gv;
                inds_ws[(size_t)bc * KTOP + it]   = (int)gi;
                scal[6] = __float_as_uint(gv); scal[7] = gi;
            }
            __syncthreads();
            lastv = __uint_as_float(scal[6]); lasti = scal[7];
            __syncthreads();
        }
    }
}

// ---------------------------------------------------------------------------
// Kernel 2: per-batch top-100 over C*K=8000 + gather + bbox epilogue
// ---------------------------------------------------------------------------
__global__ __launch_bounds__(NT2, 4)
void global_topk_kernel(const float* __restrict__ scores_ws,
                        const int* __restrict__ inds_ws,
                        const float* __restrict__ wh,
                        const float* __restrict__ reg,
                        float* __restrict__ out)
{
    constexpr int N2 = Cdim * KTOP;    // 8000
    __shared__ float    vals[N2];
    __shared__ uint32_t hist[256];
    __shared__ float    cv[CAPC];
    __shared__ uint32_t ci[CAPC];
    __shared__ float    sv[KTOP];
    __shared__ uint32_t si[KTOP];
    __shared__ uint32_t wsum[4];
    __shared__ uint32_t scal[8];

    const int tid  = threadIdx.x;
    const int lane = tid & 63;
    const int b    = blockIdx.x;

    if (tid == 0) scal[4] = 0;
    __syncthreads();
    {
        uint32_t c = 0;
        for (int i = tid; i < N2; i += NT2) {
            float v = scores_ws[(size_t)b * N2 + i];
            vals[i] = v;
            if (v > 0.0f) c++;
        }
        if (c) atomicAdd(&scal[4], c);
    }
    __syncthreads();
    const uint32_t n_pos = scal[4];
    const bool fast = (n_pos >= KTOP);

    uint32_t prefix = 0, mask = 0, rank_rem = KTOP, cnt_gt = 0, cand_total = 0;

    if (fast) {
        const int shifts[3] = {23, 15, 7};
        for (int lev = 0; lev < 3; ++lev) {
            const int shift = shifts[lev];
            if (tid < 256) hist[tid] = 0;
            __syncthreads();
            for (int i = tid; i < N2; i += NT2) {
                float v = vals[i];
                if (v > 0.0f) {
                    uint32_t key = __float_as_uint(v);
                    if ((key & mask) == prefix)
                        atomicAdd(&hist[(key >> shift) & 0xFFu], 1u);
                }
            }
            __syncthreads();
            uint32_t h = 0, s = 0;
            if (tid < 256) {
                int bin = 255 - tid;
                h = hist[bin];
                s = h;
                for (int d = 1; d < 64; d <<= 1) {
                    uint32_t nn = __shfl_up(s, d);
                    if (lane >= d) s += nn;
                }
                if (lane == 63) wsum[tid >> 6] = s;
            }
            __syncthreads();
            if (tid < 256) {
                uint32_t off = 0;
                for (int w2 = 0; w2 < (tid >> 6); ++w2) off += wsum[w2];
                s += off;
                uint32_t s_ex = s - h;
                if (s_ex < rank_rem && rank_rem <= s) {
                    scal[0] = (uint32_t)(255 - tid); scal[1] = s_ex; scal[2] = h;
                }
            }
            __syncthreads();
            prefix  |= scal[0] << shift;
            mask    |= 0xFFu << shift;
            cnt_gt  += scal[1];
            rank_rem -= scal[1];
            cand_total = cnt_gt + scal[2];
            if (cand_total <= CAPC) break;
        }
    }

    if (fast && cand_total <= CAPC) {
        if (tid == 0) scal[3] = 0;
        __syncthreads();
        for (int i = tid; i < N2; i += NT2) {
            float v = vals[i];
            if (v > 0.0f) {
                uint32_t key = __float_as_uint(v);
                if ((key & mask) >= prefix) {
                    uint32_t slot = atomicAdd(&scal[3], 1u);
                    cv[slot] = v; ci[slot] = (uint32_t)i;
                }
            }
        }
        __syncthreads();
        const uint32_t ct = scal[3];
        if (tid < (int)ct) {
            float av = cv[tid]; uint32_t ai = ci[tid];
            uint32_t rank = 0;
            for (uint32_t j2 = 0; j2 < ct; ++j2)
                rank += precedes(cv[j2], ci[j2], av, ai) ? 1u : 0u;
            if (rank < KTOP) { sv[rank] = av; si[rank] = ai; }
        }
        __syncthreads();
    } else {
        // fallback: iterative extraction over vals (marking), 16 waves
        for (int it = 0; it < KTOP; ++it) {
            float bv = -2.0f; uint32_t bi = 0xFFFFFFFFu;
            for (int i = tid; i < N2; i += NT2) {
                float v = vals[i];
                if (precedes(v, (uint32_t)i, bv, bi) && v >= -1.0f) { }
                if (v >= 0.0f && precedes(v, (uint32_t)i, bv, bi)) { bv = v; bi = (uint32_t)i; }
            }
            for (int d = 32; d > 0; d >>= 1) {
                float    ov = __shfl_xor(bv, d);
                uint32_t oi = __shfl_xor(bi, d);
                if (precedes(ov, oi, bv, bi)) { bv = ov; bi = oi; }
            }
            if (lane == 0) { hist[tid >> 6] = __float_as_uint(bv); hist[32 + (tid >> 6)] = bi; }
            __syncthreads();
            if (tid == 0) {
                float gv = __uint_as_float(hist[0]); uint32_t gi = hist[32];
                for (int w2 = 1; w2 < NT2 / 64; ++w2) {
                    float    ov = __uint_as_float(hist[w2]);
                    uint32_t oi = hist[32 + w2];
                    if (precedes(ov, oi, gv, gi)) { gv = ov; gi = oi; }
                }
                sv[it] = gv; si[it] = gi;
                vals[gi] = -1.0f;
            }
            __syncthreads();
        }
    }

    // ---- epilogue: gather + bbox ----
    if (tid < KTOP) {
        float    sc   = sv[tid];
        uint32_t ind2 = si[tid];
        uint32_t cls  = ind2 / KTOP;
        int spatial   = inds_ws[(size_t)b * N2 + ind2];
        float ysf = (float)(spatial >> 7);
        float xsf = (float)(spatial & (Wdim - 1));
        float rx = reg[((size_t)b * 2 + 0) * HW + spatial];
        float ry = reg[((size_t)b * 2 + 1) * HW + spatial];
        float ww = wh [((size_t)b * 2 + 0) * HW + spatial];
        float hh = wh [((size_t)b * 2 + 1) * HW + spatial];
        float xb = xsf + rx, yb = ysf + ry;
        float* o = out + ((size_t)b * KTOP + tid) * 6;
        o[0] = xb - ww * 0.5f;
        o[1] = yb - hh * 0.5f;
        o[2] = xb + ww * 0.5f;
        o[3] = yb + hh * 0.5f;
        o[4] = sc;
        o[5] = (float)cls;
    }
}

extern "C" void kernel_launch(void* const* d_in, const int* in_sizes, int n_in,
                              void* d_out, int out_size, void* d_ws, size_t ws_size,
                              hipStream_t stream)
{
    const float* heat = (const float*)d_in[0];
    const float* wh   = (const float*)d_in[1];
    const float* reg  = (const float*)d_in[2];
    float* out = (float*)d_out;

    float* scores_ws = (float*)d_ws;
    int*   inds_ws   = (int*)((char*)d_ws + (size_t)Bdim * Cdim * KTOP * sizeof(float));

    nms_topk_kernel<<<Bdim * Cdim, NT1, 0, stream>>>(heat, scores_ws, inds_ws);
    global_topk_kernel<<<Bdim, NT2, 0, stream>>>(scores_ws, inds_ws, wh, reg, out);
}